// Round 5
// baseline (5262.451 us; speedup 1.0000x reference)
//
#include <hip/hip_runtime.h>
#include <cmath>

#ifndef M_PI
#define M_PI 3.14159265358979323846
#endif

#define T_LEN    160000
#define NSEG     155
#define ROWS     32
#define NBANDS   8

// ---- kernel A (cascade) config ----
#define CHUNK_A  96
#define NCHUNK_A 1664                 // 96*1664 = 159744 = all samples any segment uses
#define TOT_A    (NCHUNK_A + 3)      // 4-stage pipeline drain
#define SAMP_USED 159744
#define BAND_ELEMS ((size_t)SAMP_USED * 64)        // floats per band in ws
#define LOUD_FLOATS (NBANDS * 2 * ROWS * NSEG)     // 79360

// ---- R4 fallback config ----
#define CHUNK_P  64
#define NCHUNK_P 2496
#define TOT_P    (NCHUNK_P + 2)

struct AllCoefs {
    float h[NBANDS][5];   // b0 b1 b2 a1 a2 (a0-normalized, f32-cast like np.float32)
    float l[NBANDS][5];
};

// fp32 DF-I biquad, LLVM FMA-contraction pattern of the left-associated
// reference expression — verified BIT-EXACT vs the np reference (R3/R4 absmax 0.0).
// Split below into FIR part (s2) and REC part (s3,y) — same ops, same order.
__device__ __forceinline__ float bq32(float x,
                                      const float b0, const float b1, const float b2,
                                      const float na1, const float na2,
                                      float& x1, float& x2, float& y1, float& y2) {
    float s1 = __fmaf_rn(b0, x, __fmul_rn(b1, x1));
    float s2 = __fmaf_rn(b2, x2, s1);
    float s3 = __fmaf_rn(na1, y1, s2);
    float y  = __fmaf_rn(na2, y2, s3);
    x2 = x1; x1 = x;
    y2 = y1; y1 = y;
    return y;
}

// Weighting biquad b=(1,-2,1), a=(1,-1.8f,0.81f); b-products exact pow2.
__device__ __forceinline__ void wstep(float x, float& x1, float& x2,
                                      float& y1, float& y2, float& acc) {
    const float NA1 =  1.79999995231628417969f; // -np.float32(-1.8)
    const float NA2 = -0.810000002384185791f;   // -np.float32(0.81)
    float s1 = __fadd_rn(x, __fmul_rn(-2.0f, x1));
    float s2 = __fadd_rn(s1, x2);
    float s3 = __fmaf_rn(NA1, y1, s2);
    float y  = __fmaf_rn(NA2, y2, s3);
    x2 = x1; x1 = x;
    y2 = y1; y1 = y;
    acc = __fmaf_rn(y, y, acc);
}

// ============================ Kernel A ===================================
// One block per band; 4 waves = 4-stage pipeline across the CU's SIMDs:
//   w0 hpFIR : global x -> s2_hp        (no loop-carried arithmetic dep)
//   w1 hpREC : s2_hp -> y_hp            (2 FMA/sample, the serial chain)
//   w2 lpFIR : y_hp -> s2_lp
//   w3 lpREC : s2_lp -> y_lp (GLOBAL, [t][chain] coalesced)
// Identical arithmetic ops in identical order to the bit-exact R3 kernel.
__global__ __launch_bounds__(256, 1)
void tf_cascade_kernel(const float* __restrict__ sig, const float* __restrict__ wm,
                       float* __restrict__ ylp, AllCoefs C, int band_base) {
    __shared__ float s2h[2][CHUNK_A * 64];   // hpFIR -> hpREC
    __shared__ float yh [2][CHUNK_A * 64];   // hpREC -> lpFIR
    __shared__ float s2l[2][CHUNK_A * 64];   // lpFIR -> lpREC   (total 144 KiB)

    const int bl   = blockIdx.x;
    const int band = band_base + bl;
    const int tid  = threadIdx.x;
    const int wid  = tid >> 6;
    const int lane = tid & 63;
    const int src  = lane >> 5;
    const int row  = lane & 31;

    const float hb0 = C.h[band][0], hb1 = C.h[band][1], hb2 = C.h[band][2];
    const float hna1 = -C.h[band][3], hna2 = -C.h[band][4];
    const float lb0 = C.l[band][0], lb1 = C.l[band][1], lb2 = C.l[band][2];
    const float lna1 = -C.l[band][3], lna2 = -C.l[band][4];

    const float* __restrict__ xrow = (src ? wm : sig) + (size_t)row * T_LEN;
    float* __restrict__ yg = ylp + (size_t)bl * BAND_ELEMS + lane;

    float x1 = 0.f, x2 = 0.f;   // FIR state (w0: input x, w2: y_hp)
    float y1 = 0.f, y2 = 0.f;   // REC state (w1: hp, w3: lp)

    float4 pf[CHUNK_A / 4];     // hpFIR prefetch buffer (next chunk)
    if (wid == 0) {
        const float4* p0 = (const float4*)xrow;
        #pragma unroll
        for (int i = 0; i < CHUNK_A / 4; ++i) pf[i] = p0[i];
    }

    for (int iter = 0; iter < TOT_A; ++iter) {
        if (wid == 0) {
            if (iter < NCHUNK_A) {
                const int k = iter;
                // prefetch chunk k+1: max addr 1664*96+95 = 159839 < 160000, in-bounds
                const float4* nx = (const float4*)(xrow + (size_t)(k + 1) * CHUNK_A);
                float* __restrict__ ob = s2h[k & 1];
                #pragma unroll
                for (int i = 0; i < CHUNK_A / 4; ++i) {
                    float4 v = pf[i];
                    pf[i] = nx[i];
                    float s1, s2;
                    s1 = __fmaf_rn(hb0, v.x, __fmul_rn(hb1, x1));
                    s2 = __fmaf_rn(hb2, x2, s1); ob[(4*i+0)*64 + lane] = s2; x2 = x1; x1 = v.x;
                    s1 = __fmaf_rn(hb0, v.y, __fmul_rn(hb1, x1));
                    s2 = __fmaf_rn(hb2, x2, s1); ob[(4*i+1)*64 + lane] = s2; x2 = x1; x1 = v.y;
                    s1 = __fmaf_rn(hb0, v.z, __fmul_rn(hb1, x1));
                    s2 = __fmaf_rn(hb2, x2, s1); ob[(4*i+2)*64 + lane] = s2; x2 = x1; x1 = v.z;
                    s1 = __fmaf_rn(hb0, v.w, __fmul_rn(hb1, x1));
                    s2 = __fmaf_rn(hb2, x2, s1); ob[(4*i+3)*64 + lane] = s2; x2 = x1; x1 = v.w;
                }
            }
        } else if (wid == 1) {
            if (iter >= 1 && iter <= NCHUNK_A) {
                const int c = iter - 1;
                const float* __restrict__ ib = s2h[c & 1];
                float* __restrict__ ob = yh[c & 1];
                #pragma unroll
                for (int t = 0; t < CHUNK_A; ++t) {
                    float s2 = ib[t*64 + lane];
                    float s3 = __fmaf_rn(hna1, y1, s2);
                    float y  = __fmaf_rn(hna2, y2, s3);
                    y2 = y1; y1 = y;
                    ob[t*64 + lane] = y;
                }
            }
        } else if (wid == 2) {
            if (iter >= 2 && iter <= NCHUNK_A + 1) {
                const int c = iter - 2;
                const float* __restrict__ ib = yh[c & 1];
                float* __restrict__ ob = s2l[c & 1];
                #pragma unroll
                for (int t = 0; t < CHUNK_A; ++t) {
                    float x  = ib[t*64 + lane];
                    float s1 = __fmaf_rn(lb0, x, __fmul_rn(lb1, x1));
                    float s2 = __fmaf_rn(lb2, x2, s1);
                    ob[t*64 + lane] = s2;
                    x2 = x1; x1 = x;
                }
            }
        } else {
            if (iter >= 3) {
                const int c = iter - 3;
                const float* __restrict__ ib = s2l[c & 1];
                float* __restrict__ gp = yg + (size_t)c * CHUNK_A * 64;
                #pragma unroll
                for (int t = 0; t < CHUNK_A; ++t) {
                    float s2 = ib[t*64 + lane];
                    float s3 = __fmaf_rn(lna1, y1, s2);
                    float y  = __fmaf_rn(lna2, y2, s3);
                    y2 = y1; y1 = y;
                    gp[t*64] = y;
                }
            }
        }
        __syncthreads();
    }
}

// ============================ Kernel B ===================================
// One wave per (band, segment): weighting recurrence + energy over the
// segment's 2048 samples, exact R3 op order (zero init at segment start,
// time-ordered fma(y,y,acc)). 1240 independent waves — massively parallel.
__global__ __launch_bounds__(256, 1)
void tf_weight_kernel(const float* __restrict__ ylp, float* __restrict__ loud,
                      int band_base) {
    const int bl   = blockIdx.x;
    const int band = band_base + bl;
    const int wid  = threadIdx.x >> 6;
    const int lane = threadIdx.x & 63;
    const int seg  = blockIdx.y * 4 + wid;
    if (seg >= NSEG) return;            // no barriers below; safe wave exit

    const float* __restrict__ base =
        ylp + (size_t)bl * BAND_ELEMS + (size_t)seg * 1024 * 64 + lane;

    float x1 = 0.f, x2 = 0.f, y1 = 0.f, y2 = 0.f, acc = 0.f;

    // depth-3 register prefetch ring: groups of 16 samples, 128 groups = 2048
    float buf[4][16];
    #pragma unroll
    for (int d = 0; d < 3; ++d) {
        const float* p = base + (size_t)d * 16 * 64;
        #pragma unroll
        for (int i = 0; i < 16; ++i) buf[d][i] = p[i * 64];
    }
    #pragma unroll 4
    for (int g = 0; g < 128; ++g) {
        const int slot = g & 3;
        if (g + 3 < 128) {
            const float* p = base + (size_t)(g + 3) * 16 * 64;
            #pragma unroll
            for (int i = 0; i < 16; ++i) buf[(slot + 3) & 3][i] = p[i * 64];
        }
        #pragma unroll
        for (int i = 0; i < 16; ++i) wstep(buf[slot][i], x1, x2, y1, y2, acc);
    }

    const int srcI = lane >> 5, row = lane & 31;
    float e = __fmul_rn(acc, 0.00048828125f);          // /2048 exact
    loud[((size_t)((band * 2 + srcI) * ROWS + row)) * NSEG + seg] =
        __fmul_rn(10.0f, log10f(__fadd_rn(e, 1e-8f)));
}

// ===================== R4 fallback (proven, 4.35 ms) =====================
__global__ __launch_bounds__(256, 1)
void tf_pipe_kernel(const float* __restrict__ sig, const float* __restrict__ wm,
                    float* __restrict__ loud, AllCoefs C) {
    __shared__ float ybA[2][CHUNK_P * 64];
    __shared__ float ybB[2][CHUNK_P * 64];

    const int band = blockIdx.x;
    const int tid  = threadIdx.x;
    const int wid  = tid >> 6;
    const int lane = tid & 63;
    const int src  = lane >> 5;
    const int row  = lane & 31;

    const float hb0 = C.h[band][0], hb1 = C.h[band][1], hb2 = C.h[band][2];
    const float hna1 = -C.h[band][3], hna2 = -C.h[band][4];
    const float lb0 = C.l[band][0], lb1 = C.l[band][1], lb2 = C.l[band][2];
    const float lna1 = -C.l[band][3], lna2 = -C.l[band][4];

    const float* __restrict__ xrow = (src ? wm : sig) + (size_t)row * T_LEN;
    float* __restrict__ out = loud + ((size_t)(band * 2 + src) * ROWS + row) * NSEG;

    float x1 = 0.f, x2 = 0.f, y1 = 0.f, y2 = 0.f;
    float acc = 0.f;
    const int parity = (wid == 3) ? 1 : 0;

    float4 pf[16];
    if (wid == 0) {
        const float4* p0 = (const float4*)xrow;
        #pragma unroll
        for (int i = 0; i < 16; ++i) pf[i] = p0[i];
    }

    for (int iter = 0; iter < TOT_P; ++iter) {
        if (wid == 0) {
            if (iter < NCHUNK_P) {
                const int k = iter;
                const float4* np_ = (const float4*)(xrow + (size_t)(k + 1) * CHUNK_P);
                float* __restrict__ ob = ybA[k & 1];
                #pragma unroll
                for (int i = 0; i < 16; ++i) {
                    float4 v = pf[i];
                    pf[i] = np_[i];
                    float y;
                    y = bq32(v.x, hb0,hb1,hb2,hna1,hna2, x1,x2,y1,y2); ob[(4*i+0)*64 + lane] = y;
                    y = bq32(v.y, hb0,hb1,hb2,hna1,hna2, x1,x2,y1,y2); ob[(4*i+1)*64 + lane] = y;
                    y = bq32(v.z, hb0,hb1,hb2,hna1,hna2, x1,x2,y1,y2); ob[(4*i+2)*64 + lane] = y;
                    y = bq32(v.w, hb0,hb1,hb2,hna1,hna2, x1,x2,y1,y2); ob[(4*i+3)*64 + lane] = y;
                }
            }
        } else if (wid == 1) {
            if (iter >= 1 && iter <= NCHUNK_P) {
                const int c = iter - 1;
                const float* __restrict__ ib = ybA[c & 1];
                float* __restrict__ ob = ybB[c & 1];
                #pragma unroll 8
                for (int t = 0; t < CHUNK_P; ++t) {
                    float y = bq32(ib[t*64 + lane], lb0,lb1,lb2,lna1,lna2, x1,x2,y1,y2);
                    ob[t*64 + lane] = y;
                }
            }
        } else {
            if (iter >= 2) {
                const int c = iter - 2;
                const int b = c >> 4;
                if ((c & 31) == (parity << 4) && b < NSEG) {
                    x1 = 0.f; x2 = 0.f; y1 = 0.f; y2 = 0.f; acc = 0.f;
                }
                const float* __restrict__ ib = ybB[c & 1];
                #pragma unroll 8
                for (int t = 0; t < CHUNK_P; ++t)
                    wstep(ib[t*64 + lane], x1, x2, y1, y2, acc);
                if ((c & 15) == 15) {
                    const int j = b - 1;
                    if (j >= 0 && (j & 1) == parity) {
                        float e  = __fmul_rn(acc, 0.00048828125f);
                        out[j] = __fmul_rn(10.0f, log10f(__fadd_rn(e, 1e-8f)));
                    }
                }
            }
        }
        __syncthreads();
    }
}

__global__ __launch_bounds__(256)
void tf_reduce_kernel(const float* __restrict__ loud, float* __restrict__ out) {
    __shared__ double sh[256];
    const int per_band = ROWS * NSEG;
    const int npairs   = NBANDS * per_band;
    double s = 0.0;
    for (int idx = threadIdx.x; idx < npairs; idx += 256) {
        int band = idx / per_band;
        int rs   = idx - band * per_band;
        float a = loud[(size_t)(band * 2 + 0) * per_band + rs];
        float b = loud[(size_t)(band * 2 + 1) * per_band + rs];
        s += fabs((double)b - (double)a);
    }
    sh[threadIdx.x] = s;
    __syncthreads();
    for (int off = 128; off > 0; off >>= 1) {
        if (threadIdx.x < off) sh[threadIdx.x] += sh[threadIdx.x + off];
        __syncthreads();
    }
    if (threadIdx.x == 0) out[0] = (float)(sh[0] / (double)npairs);
}

// Host-side coefficients: f64 with the reference's exact expression order,
// then cast each to f32 (mirrors tuple(np.float32(v / a0) ...)).
static void mk_hp(double cutoff, float* o) {
    const double w0    = 2.0 * M_PI * cutoff / 16000.0;
    const double alpha = sin(w0) / (2.0 * 0.707);
    const double cw    = cos(w0);
    const double b0 = (1.0 + cw) / 2.0;
    const double b1 = -(1.0 + cw);
    const double b2 = (1.0 + cw) / 2.0;
    const double a0 = 1.0 + alpha;
    const double a1 = -2.0 * cw;
    const double a2 = 1.0 - alpha;
    o[0] = (float)(b0 / a0); o[1] = (float)(b1 / a0); o[2] = (float)(b2 / a0);
    o[3] = (float)(a1 / a0); o[4] = (float)(a2 / a0);
}

static void mk_lp(double cutoff, float* o) {
    const double w0    = 2.0 * M_PI * cutoff / 16000.0;
    const double alpha = sin(w0) / (2.0 * 0.707);
    const double cw    = cos(w0);
    const double b0 = (1.0 - cw) / 2.0;
    const double b1 = 1.0 - cw;
    const double b2 = (1.0 - cw) / 2.0;
    const double a0 = 1.0 + alpha;
    const double a1 = -2.0 * cw;
    const double a2 = 1.0 - alpha;
    o[0] = (float)(b0 / a0); o[1] = (float)(b1 / a0); o[2] = (float)(b2 / a0);
    o[3] = (float)(a1 / a0); o[4] = (float)(a2 / a0);
}

extern "C" void kernel_launch(void* const* d_in, const int* in_sizes, int n_in,
                              void* d_out, int out_size, void* d_ws, size_t ws_size,
                              hipStream_t stream) {
    const float* sig = (const float*)d_in[0];
    const float* wm  = (const float*)d_in[1];

    float* loud = (float*)d_ws;                       // 317440 B
    const size_t loud_bytes = (size_t)LOUD_FLOATS * 4;
    float* ylp = (float*)((char*)d_ws + loud_bytes);

    AllCoefs C;
    for (int i = 0; i < NBANDS; ++i) {
        mk_hp(1000.0 * (double)i,       C.h[i]);
        mk_lp(1000.0 * (double)(i + 1), C.l[i]);
    }

    // ws_size is constant across calls -> branch is graph-capture-safe.
    const size_t need1 = loud_bytes + 8 * BAND_ELEMS * 4;   // ~327.5 MB
    const size_t need2 = loud_bytes + 4 * BAND_ELEMS * 4;   // ~163.9 MB

    if (ws_size >= need1) {
        tf_cascade_kernel<<<8, 256, 0, stream>>>(sig, wm, ylp, C, 0);
        tf_weight_kernel<<<dim3(8, 39), 256, 0, stream>>>(ylp, loud, 0);
    } else if (ws_size >= need2) {
        for (int p = 0; p < 2; ++p) {
            tf_cascade_kernel<<<4, 256, 0, stream>>>(sig, wm, ylp, C, 4 * p);
            tf_weight_kernel<<<dim3(4, 39), 256, 0, stream>>>(ylp, loud, 4 * p);
        }
    } else {
        tf_pipe_kernel<<<NBANDS, 256, 0, stream>>>(sig, wm, loud, C);
    }
    tf_reduce_kernel<<<1, 256, 0, stream>>>(loud, (float*)d_out);
}

// Round 6
// 4301.001 us; speedup vs baseline: 1.2235x; 1.2235x over previous
//
#include <hip/hip_runtime.h>
#include <cmath>

#ifndef M_PI
#define M_PI 3.14159265358979323846
#endif

#define T_LEN   160000
#define NSEG    155
#define ROWS    32
#define NBANDS  8

#define CHUNK   128
#define NGRP    (CHUNK / 4)          // 32 float4-groups per chunk
#define NCHUNK  1248                 // 128*1248 = 159744 = all samples any segment uses
#define TOT_IT  (NCHUNK + 3)         // 4-stage pipeline drain
#define LOUD_FLOATS (NBANDS * 2 * ROWS * NSEG)   // 79360

struct AllCoefs {
    float h[NBANDS][5];   // b0 b1 b2 a1 a2 (a0-normalized, f32-cast like np.float32)
    float l[NBANDS][5];
};

// ============================ Fused kernel ===============================
// One block per (band, src): 32 chains (rows). 4 waves = 4-stage pipeline:
//   w0 hpFIR : global x -> s2_hp                  (prefetch ring, 16 float4)
//   w1 hpREC+lpFIR : s2_hp -> s2_lp               (hp recurrence is the serial core)
//   w2 lpREC : s2_lp -> y_lp (LDS)
//   w3 weighting, BOTH parities: lanes 0-31 even segments, lanes 32-63 odd
//      (both halves broadcast-read the same chain samples — conflict-free)
// All LDS handoffs are float4-packed [group][chain] -> ds_read/write_b128,
// consecutive lanes -> consecutive 16B, conflict-free.
// Every per-chain arithmetic op is identical, in identical order, to the
// R3 kernel verified BIT-EXACT vs the np reference (absmax 0.0).
__global__ __launch_bounds__(256, 1)
void tf_fused_kernel(const float* __restrict__ sig, const float* __restrict__ wm,
                     float* __restrict__ loud, AllCoefs C) {
    __shared__ float s2h[2][NGRP * 32 * 4];   // hpFIR -> hpREC      (32 KiB)
    __shared__ float s2l[2][NGRP * 32 * 4];   // lpFIR -> lpREC      (32 KiB)
    __shared__ float ylp[2][NGRP * 32 * 4];   // lpREC -> weighting  (32 KiB)

    const int band = blockIdx.x;
    const int src  = blockIdx.y;              // 0 = signal, 1 = watermark
    const int tid  = threadIdx.x;
    const int wid  = tid >> 6;
    const int lane = tid & 63;
    const int ch   = lane & 31;               // chain = batch row

    const float hb0 = C.h[band][0], hb1 = C.h[band][1], hb2 = C.h[band][2];
    const float hna1 = -C.h[band][3], hna2 = -C.h[band][4];
    const float lb0 = C.l[band][0], lb1 = C.l[band][1], lb2 = C.l[band][2];
    const float lna1 = -C.l[band][3], lna2 = -C.l[band][4];
    const float NA1 =  1.79999995231628417969f; // -np.float32(-1.8)
    const float NA2 = -0.810000002384185791f;   // -np.float32(0.81)

    const float* __restrict__ xrow = (src ? wm : sig) + (size_t)ch * T_LEN;

    // per-wave filter state (role depends on wid)
    float x1 = 0.f, x2 = 0.f, y1 = 0.f, y2 = 0.f, acc = 0.f;

    float4 ring[16];                          // w0 global prefetch ring
    if (wid == 0 && lane < 32) {
        const float4* p0 = (const float4*)xrow;
        #pragma unroll
        for (int i = 0; i < 16; ++i) ring[i] = p0[i];
    }

    for (int iter = 0; iter < TOT_IT; ++iter) {
        if (wid == 0) {
            if (iter < NCHUNK && lane < 32) {
                const int c = iter;
                float4* __restrict__ ob = (float4*)s2h[c & 1];
                const float4* __restrict__ xg = (const float4*)xrow;
                #pragma unroll 4
                for (int g = 0; g < NGRP; ++g) {
                    const int G = c * NGRP + g;
                    float4 v = ring[G & 15];
                    // prefetch 16 groups ahead: max idx 39935+16 -> float 159807 < 160000
                    ring[G & 15] = xg[G + 16];
                    float4 o; float s1;
                    s1 = __fmaf_rn(hb0, v.x, __fmul_rn(hb1, x1));
                    o.x = __fmaf_rn(hb2, x2, s1); x2 = x1; x1 = v.x;
                    s1 = __fmaf_rn(hb0, v.y, __fmul_rn(hb1, x1));
                    o.y = __fmaf_rn(hb2, x2, s1); x2 = x1; x1 = v.y;
                    s1 = __fmaf_rn(hb0, v.z, __fmul_rn(hb1, x1));
                    o.z = __fmaf_rn(hb2, x2, s1); x2 = x1; x1 = v.z;
                    s1 = __fmaf_rn(hb0, v.w, __fmul_rn(hb1, x1));
                    o.w = __fmaf_rn(hb2, x2, s1); x2 = x1; x1 = v.w;
                    ob[g * 32 + ch] = o;
                }
            }
        } else if (wid == 1) {
            if (iter >= 1 && iter <= NCHUNK && lane < 32) {
                const int c = iter - 1;
                const float4* __restrict__ ib = (const float4*)s2h[c & 1];
                float4* __restrict__ ob = (float4*)s2l[c & 1];
                #pragma unroll 4
                for (int g = 0; g < NGRP; ++g) {
                    float4 v = ib[g * 32 + ch];
                    float4 o; float s3, yy, s1;
                    // hp recurrence (y1,y2) + lp FIR (x1,x2 delay y_hp)
                    s3 = __fmaf_rn(hna1, y1, v.x); yy = __fmaf_rn(hna2, y2, s3);
                    y2 = y1; y1 = yy;
                    s1 = __fmaf_rn(lb0, yy, __fmul_rn(lb1, x1));
                    o.x = __fmaf_rn(lb2, x2, s1); x2 = x1; x1 = yy;

                    s3 = __fmaf_rn(hna1, y1, v.y); yy = __fmaf_rn(hna2, y2, s3);
                    y2 = y1; y1 = yy;
                    s1 = __fmaf_rn(lb0, yy, __fmul_rn(lb1, x1));
                    o.y = __fmaf_rn(lb2, x2, s1); x2 = x1; x1 = yy;

                    s3 = __fmaf_rn(hna1, y1, v.z); yy = __fmaf_rn(hna2, y2, s3);
                    y2 = y1; y1 = yy;
                    s1 = __fmaf_rn(lb0, yy, __fmul_rn(lb1, x1));
                    o.z = __fmaf_rn(lb2, x2, s1); x2 = x1; x1 = yy;

                    s3 = __fmaf_rn(hna1, y1, v.w); yy = __fmaf_rn(hna2, y2, s3);
                    y2 = y1; y1 = yy;
                    s1 = __fmaf_rn(lb0, yy, __fmul_rn(lb1, x1));
                    o.w = __fmaf_rn(lb2, x2, s1); x2 = x1; x1 = yy;
                    ob[g * 32 + ch] = o;
                }
            }
        } else if (wid == 2) {
            if (iter >= 2 && iter <= NCHUNK + 1 && lane < 32) {
                const int c = iter - 2;
                const float4* __restrict__ ib = (const float4*)s2l[c & 1];
                float4* __restrict__ ob = (float4*)ylp[c & 1];
                #pragma unroll 4
                for (int g = 0; g < NGRP; ++g) {
                    float4 v = ib[g * 32 + ch];
                    float4 o; float s3;
                    s3 = __fmaf_rn(lna1, y1, v.x); o.x = __fmaf_rn(lna2, y2, s3);
                    y2 = y1; y1 = o.x;
                    s3 = __fmaf_rn(lna1, y1, v.y); o.y = __fmaf_rn(lna2, y2, s3);
                    y2 = y1; y1 = o.y;
                    s3 = __fmaf_rn(lna1, y1, v.z); o.z = __fmaf_rn(lna2, y2, s3);
                    y2 = y1; y1 = o.z;
                    s3 = __fmaf_rn(lna1, y1, v.w); o.w = __fmaf_rn(lna2, y2, s3);
                    y2 = y1; y1 = o.w;
                    ob[g * 32 + ch] = o;
                }
            }
        } else {
            if (iter >= 3) {
                const int c = iter - 3;
                const bool evenHalf = (lane < 32);
                const int m16 = c & 15;
                const int j0  = c >> 3;       // segment starting at this chunk (if any)
                // segment j starts at chunk 8j: even j -> c%16==0, odd j -> c%16==8
                if (((evenHalf && m16 == 0) || (!evenHalf && m16 == 8)) && j0 < NSEG) {
                    x1 = 0.f; x2 = 0.f; y1 = 0.f; y2 = 0.f; acc = 0.f;
                }
                const float4* __restrict__ ib = (const float4*)ylp[c & 1];
                #pragma unroll 4
                for (int g = 0; g < NGRP; ++g) {
                    float4 v = ib[g * 32 + ch];   // both halves: same addr -> broadcast
                    float s1, s2, s3, yy;
                    #define WSTEP(xx) \
                        s1 = __fadd_rn(xx, __fmul_rn(-2.0f, x1)); \
                        s2 = __fadd_rn(s1, x2); \
                        s3 = __fmaf_rn(NA1, y1, s2); \
                        yy = __fmaf_rn(NA2, y2, s3); \
                        x2 = x1; x1 = xx; y2 = y1; y1 = yy; \
                        acc = __fmaf_rn(yy, yy, acc);
                    WSTEP(v.x) WSTEP(v.y) WSTEP(v.z) WSTEP(v.w)
                    #undef WSTEP
                }
                // segment j = (c-15)/8 ends after chunk c when c%8==7
                if ((c & 7) == 7) {
                    const int j = (c - 15) >> 3;
                    if (j >= 0 && (((j & 1) == 0) == evenHalf)) {
                        float e = __fmul_rn(acc, 0.00048828125f);   // /2048 exact
                        loud[((size_t)((band * 2 + src) * ROWS + ch)) * NSEG + j] =
                            __fmul_rn(10.0f, log10f(__fadd_rn(e, 1e-8f)));
                    }
                }
            }
        }
        __syncthreads();
    }
}

__global__ __launch_bounds__(256)
void tf_reduce_kernel(const float* __restrict__ loud, float* __restrict__ out) {
    __shared__ double sh[256];
    const int per_band = ROWS * NSEG;       // 4960
    const int npairs   = NBANDS * per_band; // 39680
    double s = 0.0;
    for (int idx = threadIdx.x; idx < npairs; idx += 256) {
        int band = idx / per_band;
        int rs   = idx - band * per_band;
        float a = loud[(size_t)(band * 2 + 0) * per_band + rs];
        float b = loud[(size_t)(band * 2 + 1) * per_band + rs];
        s += fabs((double)b - (double)a);
    }
    sh[threadIdx.x] = s;
    __syncthreads();
    for (int off = 128; off > 0; off >>= 1) {
        if (threadIdx.x < off) sh[threadIdx.x] += sh[threadIdx.x + off];
        __syncthreads();
    }
    if (threadIdx.x == 0) out[0] = (float)(sh[0] / (double)npairs);
}

// Host-side coefficients: f64 with the reference's exact expression order,
// then cast each to f32 (mirrors tuple(np.float32(v / a0) ...)).
static void mk_hp(double cutoff, float* o) {
    const double w0    = 2.0 * M_PI * cutoff / 16000.0;
    const double alpha = sin(w0) / (2.0 * 0.707);
    const double cw    = cos(w0);
    const double b0 = (1.0 + cw) / 2.0;
    const double b1 = -(1.0 + cw);
    const double b2 = (1.0 + cw) / 2.0;
    const double a0 = 1.0 + alpha;
    const double a1 = -2.0 * cw;
    const double a2 = 1.0 - alpha;
    o[0] = (float)(b0 / a0); o[1] = (float)(b1 / a0); o[2] = (float)(b2 / a0);
    o[3] = (float)(a1 / a0); o[4] = (float)(a2 / a0);
}

static void mk_lp(double cutoff, float* o) {
    const double w0    = 2.0 * M_PI * cutoff / 16000.0;
    const double alpha = sin(w0) / (2.0 * 0.707);
    const double cw    = cos(w0);
    const double b0 = (1.0 - cw) / 2.0;
    const double b1 = 1.0 - cw;
    const double b2 = (1.0 - cw) / 2.0;
    const double a0 = 1.0 + alpha;
    const double a1 = -2.0 * cw;
    const double a2 = 1.0 - alpha;
    o[0] = (float)(b0 / a0); o[1] = (float)(b1 / a0); o[2] = (float)(b2 / a0);
    o[3] = (float)(a1 / a0); o[4] = (float)(a2 / a0);
}

extern "C" void kernel_launch(void* const* d_in, const int* in_sizes, int n_in,
                              void* d_out, int out_size, void* d_ws, size_t ws_size,
                              hipStream_t stream) {
    const float* sig = (const float*)d_in[0];
    const float* wm  = (const float*)d_in[1];
    float* loud = (float*)d_ws;   // 79360 floats = 310 KiB

    AllCoefs C;
    for (int i = 0; i < NBANDS; ++i) {
        mk_hp(1000.0 * (double)i,       C.h[i]);   // low_cut  = i*1000 exactly
        mk_lp(1000.0 * (double)(i + 1), C.l[i]);   // high_cut = (i+1)*1000 exactly
    }

    tf_fused_kernel<<<dim3(NBANDS, 2), 256, 0, stream>>>(sig, wm, loud, C);
    tf_reduce_kernel<<<1, 256, 0, stream>>>(loud, (float*)d_out);
}

// Round 7
// 2807.400 us; speedup vs baseline: 1.8745x; 1.5320x over previous
//
#include <hip/hip_runtime.h>
#include <cmath>

#ifndef M_PI
#define M_PI 3.14159265358979323846
#endif

#define T_LEN   160000
#define NSEG    155
#define ROWS    32
#define NBANDS  8

#define CHUNK   64
#define NPAIR   32                   // float2 pairs per chunk
#define NCHUNK  2496                 // 64*2496 = 159744 = all samples any segment uses
#define TOT_IT  (NCHUNK + 3)         // 4-stage pipeline drain
#define LOUD_FLOATS (NBANDS * 2 * ROWS * NSEG)   // 79360

struct AllCoefs {
    float h[NBANDS][5];   // b0 b1 b2 a1 a2 (a0-normalized, f32-cast like np.float32)
    float l[NBANDS][5];
};

// ============================ Fused pipeline =============================
// One block per (band, src): 32 chains. 4 waves on the CU's 4 SIMDs:
//   w0 hpFIR : global x (double-buffered reg prefetch) -> I1
//   w1 hpREC : I1 -> I2        (the serial hp recurrence, 2 fma/sample)
//   w2 lpFIR+lpREC : I2 -> I3
//   w3 weighting, dual parity: lanes 0-31 even segments, lanes 32-63 odd
// Interfaces are float2 [pair][chain] -> ds b64, banks (2ch+i)%32: 2 lanes/bank
// = conflict-free (m136: 2-way is free). Each wave loads its whole chunk into
// a fully-unrolled register array first (one LDS latency per chunk, loads
// issue back-to-back), then runs the serial compute, storing as it goes.
// Every per-chain arithmetic op is identical, in identical order, to the
// R3 kernel verified BIT-EXACT vs the np reference (absmax 0.0).
__global__ __launch_bounds__(256, 1)
void tf_pipe4_kernel(const float* __restrict__ sig, const float* __restrict__ wm,
                     float* __restrict__ loud, AllCoefs C) {
    __shared__ float I1[2][CHUNK * 32];   // hpFIR -> hpREC      (16 KiB x2 halves -> 16 KiB total per buf pair? 64*32*4*2 = 32 KiB)
    __shared__ float I2[2][CHUNK * 32];   // hpREC -> lp
    __shared__ float I3[2][CHUNK * 32];   // lp -> weighting     (total 48 KiB)

    const int band = blockIdx.x;
    const int src  = blockIdx.y;              // 0 = signal, 1 = watermark
    const int tid  = threadIdx.x;
    const int wid  = tid >> 6;
    const int lane = tid & 63;
    const int ch   = lane & 31;               // chain = batch row

    const float hb0 = C.h[band][0], hb1 = C.h[band][1], hb2 = C.h[band][2];
    const float hna1 = -C.h[band][3], hna2 = -C.h[band][4];
    const float lb0 = C.l[band][0], lb1 = C.l[band][1], lb2 = C.l[band][2];
    const float lna1 = -C.l[band][3], lna2 = -C.l[band][4];
    const float NA1 =  1.79999995231628417969f; // -np.float32(-1.8)
    const float NA2 = -0.810000002384185791f;   // -np.float32(0.81)

    const float* __restrict__ xrow = (src ? wm : sig) + (size_t)ch * T_LEN;

    float x1 = 0.f, x2 = 0.f, y1 = 0.f, y2 = 0.f, acc = 0.f;

    float4 pfA[16], pfB[16];                  // w0 global prefetch, constant-indexed
    if (wid == 0 && lane < 32) {
        const float4* p0 = (const float4*)xrow;
        #pragma unroll
        for (int i = 0; i < 16; ++i) pfA[i] = p0[i];
    }

// hpFIR body: compute chunk c from USE[], prefetch chunk c+1 into FILL[].
// Loads issue first (independent of compute); vmcnt waits land next iter.
#define W0_BODY(USE, FILL, cc)                                                   \
    {                                                                            \
        const float4* __restrict__ nx =                                          \
            (const float4*)(xrow + (size_t)((cc) + 1) * CHUNK);                  \
        _Pragma("unroll")                                                        \
        for (int i = 0; i < 16; ++i) FILL[i] = nx[i];                            \
        float2* __restrict__ ob = (float2*)I1[(cc) & 1];                         \
        _Pragma("unroll")                                                        \
        for (int i = 0; i < 16; ++i) {                                           \
            float4 v = USE[i]; float2 o; float s1;                               \
            s1 = __fmaf_rn(hb0, v.x, __fmul_rn(hb1, x1));                        \
            o.x = __fmaf_rn(hb2, x2, s1); x2 = x1; x1 = v.x;                     \
            s1 = __fmaf_rn(hb0, v.y, __fmul_rn(hb1, x1));                        \
            o.y = __fmaf_rn(hb2, x2, s1); x2 = x1; x1 = v.y;                     \
            ob[(2*i) * 32 + ch] = o;                                             \
            s1 = __fmaf_rn(hb0, v.z, __fmul_rn(hb1, x1));                        \
            o.x = __fmaf_rn(hb2, x2, s1); x2 = x1; x1 = v.z;                     \
            s1 = __fmaf_rn(hb0, v.w, __fmul_rn(hb1, x1));                        \
            o.y = __fmaf_rn(hb2, x2, s1); x2 = x1; x1 = v.w;                     \
            ob[(2*i + 1) * 32 + ch] = o;                                         \
        }                                                                        \
    }

    for (int iter = 0; iter < TOT_IT; ++iter) {
        if (wid == 0) {
            if (iter < NCHUNK && lane < 32) {
                const int c = iter;
                if ((c & 1) == 0) W0_BODY(pfA, pfB, c)
                else              W0_BODY(pfB, pfA, c)
            }
        } else if (wid == 1) {
            if (iter >= 1 && iter <= NCHUNK && lane < 32) {
                const int c = iter - 1;
                const float2* __restrict__ ib = (const float2*)I1[c & 1];
                float2* __restrict__ ob = (float2*)I2[c & 1];
                float2 v[NPAIR];
                #pragma unroll
                for (int p = 0; p < NPAIR; ++p) v[p] = ib[p * 32 + ch];
                #pragma unroll
                for (int p = 0; p < NPAIR; ++p) {
                    float2 o; float s3, yh;
                    s3 = __fmaf_rn(hna1, y1, v[p].x); yh = __fmaf_rn(hna2, y2, s3);
                    y2 = y1; y1 = yh; o.x = yh;
                    s3 = __fmaf_rn(hna1, y1, v[p].y); yh = __fmaf_rn(hna2, y2, s3);
                    y2 = y1; y1 = yh; o.y = yh;
                    ob[p * 32 + ch] = o;
                }
            }
        } else if (wid == 2) {
            if (iter >= 2 && iter <= NCHUNK + 1 && lane < 32) {
                const int c = iter - 2;
                const float2* __restrict__ ib = (const float2*)I2[c & 1];
                float2* __restrict__ ob = (float2*)I3[c & 1];
                float2 v[NPAIR];
                #pragma unroll
                for (int p = 0; p < NPAIR; ++p) v[p] = ib[p * 32 + ch];
                #pragma unroll
                for (int p = 0; p < NPAIR; ++p) {
                    float2 o; float s1, s2, s3, yl, xx;
                    xx = v[p].x;
                    s1 = __fmaf_rn(lb0, xx, __fmul_rn(lb1, x1));
                    s2 = __fmaf_rn(lb2, x2, s1); x2 = x1; x1 = xx;
                    s3 = __fmaf_rn(lna1, y1, s2); yl = __fmaf_rn(lna2, y2, s3);
                    y2 = y1; y1 = yl; o.x = yl;
                    xx = v[p].y;
                    s1 = __fmaf_rn(lb0, xx, __fmul_rn(lb1, x1));
                    s2 = __fmaf_rn(lb2, x2, s1); x2 = x1; x1 = xx;
                    s3 = __fmaf_rn(lna1, y1, s2); yl = __fmaf_rn(lna2, y2, s3);
                    y2 = y1; y1 = yl; o.y = yl;
                    ob[p * 32 + ch] = o;
                }
            }
        } else {
            if (iter >= 3) {
                const int c = iter - 3;
                const bool evenHalf = (lane < 32);
                const int m32 = c & 31;
                // segment j = c/16 starts at chunk c when c%32==0 (even j) or 16 (odd j)
                if ((m32 == (evenHalf ? 0 : 16)) && (c >> 4) < NSEG) {
                    x1 = 0.f; x2 = 0.f; y1 = 0.f; y2 = 0.f; acc = 0.f;
                }
                const float2* __restrict__ ib = (const float2*)I3[c & 1];
                float2 v[NPAIR];
                #pragma unroll
                for (int p = 0; p < NPAIR; ++p) v[p] = ib[p * 32 + ch]; // halves broadcast
                #pragma unroll
                for (int p = 0; p < NPAIR; ++p) {
                    float s1, s2, s3, yy;
                    // s1 = fma(-2,x1,x) == add(x, mul(-2,x1)): product exact -> bit-identical
                    #define WSTEP(xx) \
                        s1 = __fmaf_rn(-2.0f, x1, xx); \
                        s2 = __fadd_rn(s1, x2); \
                        s3 = __fmaf_rn(NA1, y1, s2); \
                        yy = __fmaf_rn(NA2, y2, s3); \
                        x2 = x1; x1 = xx; y2 = y1; y1 = yy; \
                        acc = __fmaf_rn(yy, yy, acc);
                    WSTEP(v[p].x) WSTEP(v[p].y)
                    #undef WSTEP
                }
                // even seg ends when c%32==31; odd seg ends when c%32==15 (c>=31); j=(c-31)/16
                const int endm = evenHalf ? 31 : 15;
                if (m32 == endm && c >= 31) {
                    const int j = (c - 31) >> 4;
                    float e = __fmul_rn(acc, 0.00048828125f);   // /2048 exact
                    loud[((size_t)((band * 2 + src) * ROWS + ch)) * NSEG + j] =
                        __fmul_rn(10.0f, log10f(__fadd_rn(e, 1e-8f)));
                }
            }
        }
        __syncthreads();
    }
#undef W0_BODY
}

__global__ __launch_bounds__(256)
void tf_reduce_kernel(const float* __restrict__ loud, float* __restrict__ out) {
    __shared__ double sh[256];
    const int per_band = ROWS * NSEG;       // 4960
    const int npairs   = NBANDS * per_band; // 39680
    double s = 0.0;
    for (int idx = threadIdx.x; idx < npairs; idx += 256) {
        int band = idx / per_band;
        int rs   = idx - band * per_band;
        float a = loud[(size_t)(band * 2 + 0) * per_band + rs];
        float b = loud[(size_t)(band * 2 + 1) * per_band + rs];
        s += fabs((double)b - (double)a);
    }
    sh[threadIdx.x] = s;
    __syncthreads();
    for (int off = 128; off > 0; off >>= 1) {
        if (threadIdx.x < off) sh[threadIdx.x] += sh[threadIdx.x + off];
        __syncthreads();
    }
    if (threadIdx.x == 0) out[0] = (float)(sh[0] / (double)npairs);
}

// Host-side coefficients: f64 with the reference's exact expression order,
// then cast each to f32 (mirrors tuple(np.float32(v / a0) ...)).
static void mk_hp(double cutoff, float* o) {
    const double w0    = 2.0 * M_PI * cutoff / 16000.0;
    const double alpha = sin(w0) / (2.0 * 0.707);
    const double cw    = cos(w0);
    const double b0 = (1.0 + cw) / 2.0;
    const double b1 = -(1.0 + cw);
    const double b2 = (1.0 + cw) / 2.0;
    const double a0 = 1.0 + alpha;
    const double a1 = -2.0 * cw;
    const double a2 = 1.0 - alpha;
    o[0] = (float)(b0 / a0); o[1] = (float)(b1 / a0); o[2] = (float)(b2 / a0);
    o[3] = (float)(a1 / a0); o[4] = (float)(a2 / a0);
}

static void mk_lp(double cutoff, float* o) {
    const double w0    = 2.0 * M_PI * cutoff / 16000.0;
    const double alpha = sin(w0) / (2.0 * 0.707);
    const double cw    = cos(w0);
    const double b0 = (1.0 - cw) / 2.0;
    const double b1 = 1.0 - cw;
    const double b2 = (1.0 - cw) / 2.0;
    const double a0 = 1.0 + alpha;
    const double a1 = -2.0 * cw;
    const double a2 = 1.0 - alpha;
    o[0] = (float)(b0 / a0); o[1] = (float)(b1 / a0); o[2] = (float)(b2 / a0);
    o[3] = (float)(a1 / a0); o[4] = (float)(a2 / a0);
}

extern "C" void kernel_launch(void* const* d_in, const int* in_sizes, int n_in,
                              void* d_out, int out_size, void* d_ws, size_t ws_size,
                              hipStream_t stream) {
    const float* sig = (const float*)d_in[0];
    const float* wm  = (const float*)d_in[1];
    float* loud = (float*)d_ws;   // 79360 floats = 310 KiB

    AllCoefs C;
    for (int i = 0; i < NBANDS; ++i) {
        mk_hp(1000.0 * (double)i,       C.h[i]);   // low_cut  = i*1000 exactly
        mk_lp(1000.0 * (double)(i + 1), C.l[i]);   // high_cut = (i+1)*1000 exactly
    }

    tf_pipe4_kernel<<<dim3(NBANDS, 2), 256, 0, stream>>>(sig, wm, loud, C);
    tf_reduce_kernel<<<1, 256, 0, stream>>>(loud, (float*)d_out);
}

// Round 8
// 2756.784 us; speedup vs baseline: 1.9089x; 1.0184x over previous
//
#include <hip/hip_runtime.h>
#include <cmath>

#ifndef M_PI
#define M_PI 3.14159265358979323846
#endif

#define T_LEN   160000
#define NSEG    155
#define ROWS    32
#define NBANDS  8

#define CHUNK   64
#define NQ      16                   // float4 quads per chunk
#define NCHUNK  2496                 // 64*2496 = 159744 = all samples any segment uses
#define TOT_IT  (NCHUNK + 2)         // 3-stage pipeline drain
#define LOUD_FLOATS (NBANDS * 2 * ROWS * NSEG)   // 79360

struct AllCoefs {
    float h[NBANDS][5];   // b0 b1 b2 a1 a2 (a0-normalized, f32-cast like np.float32)
    float l[NBANDS][5];
};

// ============================ Fused pipeline =============================
// One block per (band, src): 32 chains, 3 waves (192 thr) on 3 of the CU's
// 4 SIMDs. FIR ops are folded into the recurrence waves' idle issue slots
// (the 8-cyc y-chain leaves ~6 spare issue cyc/sample):
//   w0 : hpFIR + hpREC   global x (ping-pong reg prefetch) -> I1
//   w1 : lpFIR + lpREC   I1 -> I2
//   w2 : weighting, dual parity: lanes 0-31 even segments, 32-63 odd
//        (halves broadcast-read the same chain data — free)
// Interfaces are float4 [quad][chain] -> ds b128 (4 samples/lane): 16 insts
// per interface-op; only 2 interfaces -> ~64 LDS insts/chunk (R7: 192 b64).
// Every per-chain arithmetic op is identical, in identical order, to the
// R3/R7 kernel verified BIT-EXACT vs the np reference (absmax 0.0).
__global__ __launch_bounds__(192, 1)
void tf_pipe3_kernel(const float* __restrict__ sig, const float* __restrict__ wm,
                     float* __restrict__ loud, AllCoefs C) {
    __shared__ float I1[2][CHUNK * 32];   // hp -> lp       (16 KiB)
    __shared__ float I2[2][CHUNK * 32];   // lp -> weight   (16 KiB)

    const int band = blockIdx.x;
    const int src  = blockIdx.y;              // 0 = signal, 1 = watermark
    const int tid  = threadIdx.x;
    const int wid  = tid >> 6;
    const int lane = tid & 63;
    const int ch   = lane & 31;               // chain = batch row

    const float hb0 = C.h[band][0], hb1 = C.h[band][1], hb2 = C.h[band][2];
    const float hna1 = -C.h[band][3], hna2 = -C.h[band][4];
    const float lb0 = C.l[band][0], lb1 = C.l[band][1], lb2 = C.l[band][2];
    const float lna1 = -C.l[band][3], lna2 = -C.l[band][4];
    const float NA1 =  1.79999995231628417969f; // -np.float32(-1.8)
    const float NA2 = -0.810000002384185791f;   // -np.float32(0.81)

    const float* __restrict__ xrow = (src ? wm : sig) + (size_t)ch * T_LEN;

    float x1 = 0.f, x2 = 0.f, y1 = 0.f, y2 = 0.f, acc = 0.f;

    float4 pfA[NQ], pfB[NQ];                  // w0 global prefetch, constant-indexed
    if (wid == 0 && lane < 32) {
        const float4* p0 = (const float4*)xrow;
        #pragma unroll
        for (int i = 0; i < NQ; ++i) pfA[i] = p0[i];
    }

// hpFIR+hpREC: compute chunk cc from USE[], prefetch chunk cc+1 into FILL[].
#define HP1(xx, oo)                                                          \
    {  float s1 = __fmaf_rn(hb0, xx, __fmul_rn(hb1, x1));                    \
       float s2 = __fmaf_rn(hb2, x2, s1); x2 = x1; x1 = xx;                  \
       float s3 = __fmaf_rn(hna1, y1, s2);                                   \
       oo = __fmaf_rn(hna2, y2, s3); y2 = y1; y1 = oo; }
#define W0_BODY(USE, FILL, cc)                                               \
    {                                                                        \
        const float4* __restrict__ nx =                                      \
            (const float4*)(xrow + (size_t)((cc) + 1) * CHUNK);              \
        _Pragma("unroll")                                                    \
        for (int i = 0; i < NQ; ++i) FILL[i] = nx[i];                        \
        float4* __restrict__ ob = (float4*)I1[(cc) & 1];                     \
        _Pragma("unroll")                                                    \
        for (int i = 0; i < NQ; ++i) {                                       \
            float4 v = USE[i]; float4 o;                                     \
            HP1(v.x, o.x) HP1(v.y, o.y) HP1(v.z, o.z) HP1(v.w, o.w)          \
            ob[i * 32 + ch] = o;                                             \
        }                                                                    \
    }

    for (int iter = 0; iter < TOT_IT; ++iter) {
        if (wid == 0) {
            if (iter < NCHUNK && lane < 32) {
                const int c = iter;
                if ((c & 1) == 0) W0_BODY(pfA, pfB, c)
                else              W0_BODY(pfB, pfA, c)
            }
        } else if (wid == 1) {
            if (iter >= 1 && iter <= NCHUNK && lane < 32) {
                const int c = iter - 1;
                const float4* __restrict__ ib = (const float4*)I1[c & 1];
                float4* __restrict__ ob = (float4*)I2[c & 1];
                float4 v[NQ];
                #pragma unroll
                for (int i = 0; i < NQ; ++i) v[i] = ib[i * 32 + ch];
                #pragma unroll
                for (int i = 0; i < NQ; ++i) {
                    float4 o;
                    #define LP1(xx, oo) \
                        { float s1 = __fmaf_rn(lb0, xx, __fmul_rn(lb1, x1)); \
                          float s2 = __fmaf_rn(lb2, x2, s1); x2 = x1; x1 = xx; \
                          float s3 = __fmaf_rn(lna1, y1, s2); \
                          oo = __fmaf_rn(lna2, y2, s3); y2 = y1; y1 = oo; }
                    LP1(v[i].x, o.x) LP1(v[i].y, o.y) LP1(v[i].z, o.z) LP1(v[i].w, o.w)
                    #undef LP1
                    ob[i * 32 + ch] = o;
                }
            }
        } else {
            if (iter >= 2) {
                const int c = iter - 2;
                const bool evenHalf = (lane < 32);
                const int m32 = c & 31;
                // segment j = c/16 starts at chunk c when c%32==0 (even j) or 16 (odd j)
                if ((m32 == (evenHalf ? 0 : 16)) && (c >> 4) < NSEG) {
                    x1 = 0.f; x2 = 0.f; y1 = 0.f; y2 = 0.f; acc = 0.f;
                }
                const float4* __restrict__ ib = (const float4*)I2[c & 1];
                float4 v[NQ];
                #pragma unroll
                for (int i = 0; i < NQ; ++i) v[i] = ib[i * 32 + ch]; // halves broadcast
                #pragma unroll
                for (int i = 0; i < NQ; ++i) {
                    float s1, s2, s3, yy;
                    // s1 = fma(-2,x1,x): product exact -> bit-identical to add form
                    #define WSTEP(xx) \
                        s1 = __fmaf_rn(-2.0f, x1, xx); \
                        s2 = __fadd_rn(s1, x2); \
                        s3 = __fmaf_rn(NA1, y1, s2); \
                        yy = __fmaf_rn(NA2, y2, s3); \
                        x2 = x1; x1 = xx; y2 = y1; y1 = yy; \
                        acc = __fmaf_rn(yy, yy, acc);
                    WSTEP(v[i].x) WSTEP(v[i].y) WSTEP(v[i].z) WSTEP(v[i].w)
                    #undef WSTEP
                }
                // even seg ends when c%32==31; odd seg when c%32==15 (c>=31); j=(c-31)/16
                const int endm = evenHalf ? 31 : 15;
                if (m32 == endm && c >= 31) {
                    const int j = (c - 31) >> 4;
                    float e = __fmul_rn(acc, 0.00048828125f);   // /2048 exact
                    loud[((size_t)((band * 2 + src) * ROWS + ch)) * NSEG + j] =
                        __fmul_rn(10.0f, log10f(__fadd_rn(e, 1e-8f)));
                }
            }
        }
        __syncthreads();
    }
#undef W0_BODY
#undef HP1
}

__global__ __launch_bounds__(256)
void tf_reduce_kernel(const float* __restrict__ loud, float* __restrict__ out) {
    __shared__ double sh[256];
    const int per_band = ROWS * NSEG;       // 4960
    const int npairs   = NBANDS * per_band; // 39680
    double s = 0.0;
    for (int idx = threadIdx.x; idx < npairs; idx += 256) {
        int band = idx / per_band;
        int rs   = idx - band * per_band;
        float a = loud[(size_t)(band * 2 + 0) * per_band + rs];
        float b = loud[(size_t)(band * 2 + 1) * per_band + rs];
        s += fabs((double)b - (double)a);
    }
    sh[threadIdx.x] = s;
    __syncthreads();
    for (int off = 128; off > 0; off >>= 1) {
        if (threadIdx.x < off) sh[threadIdx.x] += sh[threadIdx.x + off];
        __syncthreads();
    }
    if (threadIdx.x == 0) out[0] = (float)(sh[0] / (double)npairs);
}

// Host-side coefficients: f64 with the reference's exact expression order,
// then cast each to f32 (mirrors tuple(np.float32(v / a0) ...)).
static void mk_hp(double cutoff, float* o) {
    const double w0    = 2.0 * M_PI * cutoff / 16000.0;
    const double alpha = sin(w0) / (2.0 * 0.707);
    const double cw    = cos(w0);
    const double b0 = (1.0 + cw) / 2.0;
    const double b1 = -(1.0 + cw);
    const double b2 = (1.0 + cw) / 2.0;
    const double a0 = 1.0 + alpha;
    const double a1 = -2.0 * cw;
    const double a2 = 1.0 - alpha;
    o[0] = (float)(b0 / a0); o[1] = (float)(b1 / a0); o[2] = (float)(b2 / a0);
    o[3] = (float)(a1 / a0); o[4] = (float)(a2 / a0);
}

static void mk_lp(double cutoff, float* o) {
    const double w0    = 2.0 * M_PI * cutoff / 16000.0;
    const double alpha = sin(w0) / (2.0 * 0.707);
    const double cw    = cos(w0);
    const double b0 = (1.0 - cw) / 2.0;
    const double b1 = 1.0 - cw;
    const double b2 = (1.0 - cw) / 2.0;
    const double a0 = 1.0 + alpha;
    const double a1 = -2.0 * cw;
    const double a2 = 1.0 - alpha;
    o[0] = (float)(b0 / a0); o[1] = (float)(b1 / a0); o[2] = (float)(b2 / a0);
    o[3] = (float)(a1 / a0); o[4] = (float)(a2 / a0);
}

extern "C" void kernel_launch(void* const* d_in, const int* in_sizes, int n_in,
                              void* d_out, int out_size, void* d_ws, size_t ws_size,
                              hipStream_t stream) {
    const float* sig = (const float*)d_in[0];
    const float* wm  = (const float*)d_in[1];
    float* loud = (float*)d_ws;   // 79360 floats = 310 KiB

    AllCoefs C;
    for (int i = 0; i < NBANDS; ++i) {
        mk_hp(1000.0 * (double)i,       C.h[i]);   // low_cut  = i*1000 exactly
        mk_lp(1000.0 * (double)(i + 1), C.l[i]);   // high_cut = (i+1)*1000 exactly
    }

    tf_pipe3_kernel<<<dim3(NBANDS, 2), 192, 0, stream>>>(sig, wm, loud, C);
    tf_reduce_kernel<<<1, 256, 0, stream>>>(loud, (float*)d_out);
}